// Round 1
// baseline (355.341 us; speedup 1.0000x reference)
//
#include <hip/hip_runtime.h>
#include <hip/hip_bf16.h>

#define B_  32
#define T_  2048
#define DH_ 1024
#define DS_ 1024
#define A_  512
#define M_  (B_ * T_)   // 65536

typedef __attribute__((ext_vector_type(8))) short bf16x8;
typedef __attribute__((ext_vector_type(4))) float f32x4;

__device__ __forceinline__ unsigned short f2bf(float f) {
    union { float f; unsigned u; } v; v.f = f;
    unsigned r = 0x7FFFu + ((v.u >> 16) & 1u);
    return (unsigned short)((v.u + r) >> 16);
}

__device__ __forceinline__ float fast_tanh(float x) {
    float cx = fminf(fmaxf(x, -9.f), 9.f);
    float e2 = __expf(2.f * cx);
    return (e2 - 1.f) / (e2 + 1.f);
}

// ---- kernel 0: zero e [M_] and c [B_*DH_] -------------------------------
__global__ void zero_kernel(float* __restrict__ e, float* __restrict__ c) {
    int i = blockIdx.x * blockDim.x + threadIdx.x;
    if (i < M_) e[i] = 0.f;
    int j = i - M_;
    if (j >= 0 && j < B_ * DH_) c[j] = 0.f;
}

// ---- kernel 1: U_t[a][k] = bf16(U_a[k][a]) ------------------------------
__global__ void prep_ut(const float* __restrict__ U, unsigned short* __restrict__ Ut) {
    int o = blockIdx.x * 256 + threadIdx.x;   // o < A_*DH_
    int a = o >> 10, k = o & (DH_ - 1);
    Ut[o] = f2bf(U[k * A_ + a]);
}

// ---- kernel 2: Ws[b][a] = s[b,:] . W_a[:,a] -----------------------------
__global__ void ws_gemv(const float* __restrict__ s, const float* __restrict__ W,
                        float* __restrict__ Ws) {
    int idx = blockIdx.x * 256 + threadIdx.x;   // idx < B_*A_
    int b = idx >> 9, a = idx & (A_ - 1);
    const float* sp = s + b * DS_;
    float acc = 0.f;
#pragma unroll 4
    for (int k = 0; k < DS_; ++k) acc += sp[k] * W[k * A_ + a];
    Ws[idx] = acc;
}

// ---- kernel 3: main MFMA GEMM + fused tanh/v reduction into e -----------
// 128x128 tile, BK=32, 4 waves (2x2), mfma_f32_16x16x32_bf16
__global__ void gemm_e(const float* __restrict__ h, const unsigned short* __restrict__ Ut,
                       const float* __restrict__ Ws, const float* __restrict__ va,
                       float* __restrict__ e) {
    __shared__ unsigned short As[2][128][40];   // pad to 40 bf16 = 80 B (16B aligned rows)
    __shared__ unsigned short Bs[2][128][40];

    const int tid = threadIdx.x;
    const int bid = blockIdx.x;
    const int tn = bid & 3, tm = bid >> 2;          // 4 n-tiles fast -> A-panel L2 reuse
    const int rowBase = tm * 128, nBase = tn * 128;
    const int wid = tid >> 6, lane = tid & 63;
    const int wm = wid >> 1, wn = wid & 1;
    const int lr = lane & 15, kg = lane >> 4;

    const int sr = tid >> 3;          // 0..31 staging row
    const int kq = (tid & 7) << 2;    // 0,4,..,28 staging k

    f32x4 acc[4][4];
#pragma unroll
    for (int i = 0; i < 4; ++i)
#pragma unroll
        for (int j = 0; j < 4; ++j) acc[i][j] = (f32x4){0.f, 0.f, 0.f, 0.f};

    auto stage = [&](int buf, int k0) {
#pragma unroll
        for (int p = 0; p < 4; ++p) {
            int row = p * 32 + sr;
            const float4 hv = *(const float4*)(h + (size_t)(rowBase + row) * DH_ + k0 + kq);
            ushort4 u;
            u.x = f2bf(hv.x); u.y = f2bf(hv.y); u.z = f2bf(hv.z); u.w = f2bf(hv.w);
            *(ushort4*)(&As[buf][row][kq]) = u;
            ushort4 bv = *(const ushort4*)(Ut + (size_t)(nBase + row) * DH_ + k0 + kq);
            *(ushort4*)(&Bs[buf][row][kq]) = bv;
        }
    };

    stage(0, 0);
    __syncthreads();

#pragma unroll 1
    for (int kt = 0; kt < DH_ / 32; ++kt) {
        int buf = kt & 1;
        if (kt < DH_ / 32 - 1) stage(buf ^ 1, (kt + 1) * 32);

        bf16x8 af[4], bfv[4];
#pragma unroll
        for (int mi = 0; mi < 4; ++mi)
            af[mi] = *(const bf16x8*)(&As[buf][wm * 64 + mi * 16 + lr][kg * 8]);
#pragma unroll
        for (int ni = 0; ni < 4; ++ni)
            bfv[ni] = *(const bf16x8*)(&Bs[buf][wn * 64 + ni * 16 + lr][kg * 8]);
#pragma unroll
        for (int mi = 0; mi < 4; ++mi)
#pragma unroll
            for (int ni = 0; ni < 4; ++ni)
                acc[mi][ni] = __builtin_amdgcn_mfma_f32_16x16x32_bf16(
                    af[mi], bfv[ni], acc[mi][ni], 0, 0, 0);
        __syncthreads();
    }

    // epilogue: e[row] += sum_a tanh(acc + Ws[b][a]) * v[a]  (partial over this n-tile)
    const int bIdx = rowBase >> 11;              // batch index (128-row tile within one b)
    const float* WsRow = Ws + bIdx * A_;
    float wsv[4], vav[4];
#pragma unroll
    for (int ni = 0; ni < 4; ++ni) {
        int a = nBase + wn * 64 + ni * 16 + lr;
        wsv[ni] = WsRow[a];
        vav[ni] = va[a];
    }
#pragma unroll
    for (int mi = 0; mi < 4; ++mi) {
#pragma unroll
        for (int j = 0; j < 4; ++j) {
            float ssum = 0.f;
#pragma unroll
            for (int ni = 0; ni < 4; ++ni) {
                float x = acc[mi][ni][j] + wsv[ni];
                ssum += fast_tanh(x) * vav[ni];
            }
            ssum += __shfl_xor(ssum, 1);
            ssum += __shfl_xor(ssum, 2);
            ssum += __shfl_xor(ssum, 4);
            ssum += __shfl_xor(ssum, 8);
            if (lr == 0) {
                int row = rowBase + wm * 64 + mi * 16 + (lane >> 4) * 4 + j;
                atomicAdd(&e[row], ssum);
            }
        }
    }
}

// ---- kernel 4: softmax over T per batch (in place on e) -----------------
__global__ void softmax_kernel(float* __restrict__ e) {
    __shared__ float red[8];
    const int b = blockIdx.x, tid = threadIdx.x;
    float* ep = e + b * T_;
    float4 v0 = ((float4*)ep)[tid * 2];
    float4 v1 = ((float4*)ep)[tid * 2 + 1];
    float m = fmaxf(fmaxf(fmaxf(v0.x, v0.y), fmaxf(v0.z, v0.w)),
                    fmaxf(fmaxf(v1.x, v1.y), fmaxf(v1.z, v1.w)));
#pragma unroll
    for (int off = 1; off < 64; off <<= 1) m = fmaxf(m, __shfl_xor(m, off));
    int wid = tid >> 6;
    if ((tid & 63) == 0) red[wid] = m;
    __syncthreads();
    m = fmaxf(fmaxf(red[0], red[1]), fmaxf(red[2], red[3]));
    v0.x = __expf(v0.x - m); v0.y = __expf(v0.y - m);
    v0.z = __expf(v0.z - m); v0.w = __expf(v0.w - m);
    v1.x = __expf(v1.x - m); v1.y = __expf(v1.y - m);
    v1.z = __expf(v1.z - m); v1.w = __expf(v1.w - m);
    float ssum = v0.x + v0.y + v0.z + v0.w + v1.x + v1.y + v1.z + v1.w;
#pragma unroll
    for (int off = 1; off < 64; off <<= 1) ssum += __shfl_xor(ssum, off);
    if ((tid & 63) == 0) red[4 + wid] = ssum;
    __syncthreads();
    float inv = 1.f / (red[4] + red[5] + red[6] + red[7]);
    v0.x *= inv; v0.y *= inv; v0.z *= inv; v0.w *= inv;
    v1.x *= inv; v1.y *= inv; v1.z *= inv; v1.w *= inv;
    ((float4*)ep)[tid * 2] = v0;
    ((float4*)ep)[tid * 2 + 1] = v1;
}

// ---- kernel 5: c[b][d] = sum_t a[b][t] * h[b][t][d] ---------------------
__global__ void ctx_kernel(const float* __restrict__ h, const float* __restrict__ a,
                           float* __restrict__ c) {
    const int bid = blockIdx.x;
    const int b = bid >> 5, seg = bid & 31;   // 32 t-segments of 64
    const int tid = threadIdx.x;
    const int t0 = seg * 64;
    float4 acc = {0.f, 0.f, 0.f, 0.f};
    const float* hp = h + ((size_t)b * T_ + t0) * DH_ + tid * 4;
    const float* ap = a + b * T_ + t0;
#pragma unroll 4
    for (int t = 0; t < 64; ++t) {
        float w = ap[t];
        float4 hv = *(const float4*)(hp + (size_t)t * DH_);
        acc.x += w * hv.x; acc.y += w * hv.y;
        acc.z += w * hv.z; acc.w += w * hv.w;
    }
    float* cp = c + b * DH_ + tid * 4;
    atomicAdd(cp + 0, acc.x);
    atomicAdd(cp + 1, acc.y);
    atomicAdd(cp + 2, acc.z);
    atomicAdd(cp + 3, acc.w);
}

extern "C" void kernel_launch(void* const* d_in, const int* in_sizes, int n_in,
                              void* d_out, int out_size, void* d_ws, size_t ws_size,
                              hipStream_t stream) {
    const float* s   = (const float*)d_in[0];
    const float* h   = (const float*)d_in[1];
    const float* W_a = (const float*)d_in[2];
    const float* U_a = (const float*)d_in[3];
    const float* v_a = (const float*)d_in[4];
    float* c = (float*)d_out;

    // workspace: e [65536 f32] | Ws [16384 f32] | Ut [524288 bf16]  (~1.31 MB)
    float* e  = (float*)d_ws;
    float* Ws = e + M_;
    unsigned short* Ut = (unsigned short*)(Ws + B_ * A_);

    zero_kernel<<<(M_ + B_ * DH_ + 255) / 256, 256, 0, stream>>>(e, c);
    prep_ut<<<(A_ * DH_) / 256, 256, 0, stream>>>(U_a, Ut);
    ws_gemv<<<(B_ * A_) / 256, 256, 0, stream>>>(s, W_a, Ws);
    gemm_e<<<(M_ / 128) * (A_ / 128), 256, 0, stream>>>(h, Ut, Ws, v_a, e);
    softmax_kernel<<<B_, 256, 0, stream>>>(e);
    ctx_kernel<<<B_ * 32, 256, 0, stream>>>(h, e, c);
}